// Round 1
// baseline (426.895 us; speedup 1.0000x reference)
//
#include <hip/hip_runtime.h>
#include <hip/hip_fp16.h>
#include <cstdint>

typedef int v4i __attribute__((ext_vector_type(4)));

#define AS1C(p) ((const __attribute__((address_space(1))) void*)(p))
#define AS3(p)  ((__attribute__((address_space(3))) void*)(p))

// ---------------------------------------------------------------------------
// Per-row symmetric int8 quantization: scale = max|row| / 127, q = rint(x/scale)
// One block per row, 256 threads. Two-phase (absmax, then quantize) — the row
// (16 KB) stays in L1 between phases.
// ---------------------------------------------------------------------------
__global__ __launch_bounds__(256) void quant_rows(const float* __restrict__ X,
                                                  int8_t* __restrict__ Q,
                                                  float* __restrict__ scales,
                                                  int K) {
    const int row = blockIdx.x;
    const float4* xv = (const float4*)(X + (size_t)row * K);
    const int nv = K >> 2;  // 1024

    float m = 0.0f;
    for (int i = threadIdx.x; i < nv; i += 256) {
        float4 v = xv[i];
        m = fmaxf(m, fabsf(v.x));
        m = fmaxf(m, fabsf(v.y));
        m = fmaxf(m, fabsf(v.z));
        m = fmaxf(m, fabsf(v.w));
    }
    // wave-64 butterfly reduce
    for (int off = 32; off > 0; off >>= 1)
        m = fmaxf(m, __shfl_xor(m, off, 64));

    __shared__ float wmax[4];
    __shared__ float s_sc;
    const int lane = threadIdx.x & 63;
    const int wv = threadIdx.x >> 6;
    if (lane == 0) wmax[wv] = m;
    __syncthreads();
    if (threadIdx.x == 0) {
        float mm = fmaxf(fmaxf(wmax[0], wmax[1]), fmaxf(wmax[2], wmax[3]));
        float sc = mm / 127.0f;
        scales[row] = sc;
        s_sc = sc;
    }
    __syncthreads();
    const float sc = s_sc;

    char4* qv = (char4*)(Q + (size_t)row * K);
    for (int i = threadIdx.x; i < nv; i += 256) {
        float4 v = xv[i];
        char4 q;
        q.x = (signed char)(int)rintf(v.x / sc);  // rintf = RNE, matches jnp.round
        q.y = (signed char)(int)rintf(v.y / sc);
        q.z = (signed char)(int)rintf(v.z / sc);
        q.w = (signed char)(int)rintf(v.w / sc);
        qv[i] = q;
    }
}

// ---------------------------------------------------------------------------
// int8 GEMM: C[t,o] = sum_k Aq[t,k] * Bq[o,k]  (both K-contiguous, B^T layout)
// 128x128 block tile, 256 threads = 4 waves in 2x2, each wave 64x64 = 4x4
// mfma_i32_16x16x64_i8 tiles. BK = 64 bytes. global_load_lds width-16 staging
// (m97 pattern — LDS dest is wave-uniform base + lane*16, so the LDS layout is
// exactly row*64 + (lane&3)*16 with 4 lanes/row, 16 rows/wave/issue).
// Epilogue dequant: out = fp16(acc * a_scale[t] * w_scale[o]) stored as f32.
// ---------------------------------------------------------------------------
__global__ __launch_bounds__(256) void gemm_i8(const int8_t* __restrict__ Aq,
                                               const int8_t* __restrict__ Bq,
                                               const float* __restrict__ a_scale,
                                               const float* __restrict__ w_scale,
                                               float* __restrict__ out) {
    __shared__ __align__(16) int8_t lA[128 * 64];
    __shared__ __align__(16) int8_t lB[128 * 64];

    const int n0 = blockIdx.x * 128;
    const int m0 = blockIdx.y * 128;
    const int tid = threadIdx.x;
    const int lane = tid & 63;
    const int wv = tid >> 6;       // wave id 0..3
    const int wm = wv & 1;         // wave row (2x2)
    const int wn = wv >> 1;        // wave col

    // staging: 4 lanes per 64B row, 16 rows per wave per issue
    const int srow = lane >> 2;            // 0..15
    const int scolb = (lane & 3) << 4;     // 0,16,32,48

    const int8_t* gA = Aq + (size_t)(m0 + wv * 16 + srow) * 4096 + scolb;
    const int8_t* gB = Bq + (size_t)(n0 + wv * 16 + srow) * 4096 + scolb;
    int8_t* lAw = lA + wv * 16 * 64;   // wave-uniform LDS base
    int8_t* lBw = lB + wv * 16 * 64;

    v4i acc[4][4] = {};  // 64 acc regs

    const int koff = (lane >> 4) << 4;  // 16B K-chunk per lane quad
    const int rsel = lane & 15;

    for (int k0 = 0; k0 < 4096; k0 += 64) {
        __syncthreads();  // previous iter's frag reads done before overwrite
        __builtin_amdgcn_global_load_lds(AS1C(gA + k0), AS3(lAw), 16, 0, 0);
        __builtin_amdgcn_global_load_lds(AS1C(gA + k0 + (size_t)64 * 4096), AS3(lAw + 64 * 64), 16, 0, 0);
        __builtin_amdgcn_global_load_lds(AS1C(gB + k0), AS3(lBw), 16, 0, 0);
        __builtin_amdgcn_global_load_lds(AS1C(gB + k0 + (size_t)64 * 4096), AS3(lBw + 64 * 64), 16, 0, 0);
        __syncthreads();  // compiler drains vmcnt(0) here

        v4i aF[4], bF[4];
#pragma unroll
        for (int mt = 0; mt < 4; ++mt)
            aF[mt] = *(const v4i*)&lA[(wm * 64 + mt * 16 + rsel) * 64 + koff];
#pragma unroll
        for (int nt = 0; nt < 4; ++nt)
            bF[nt] = *(const v4i*)&lB[(wn * 64 + nt * 16 + rsel) * 64 + koff];

#pragma unroll
        for (int mt = 0; mt < 4; ++mt)
#pragma unroll
            for (int nt = 0; nt < 4; ++nt)
                acc[mt][nt] = __builtin_amdgcn_mfma_i32_16x16x64_i8(
                    aF[mt], bF[nt], acc[mt][nt], 0, 0, 0);
    }

    // epilogue: C/D layout col = lane&15 (N), row = (lane>>4)*4 + reg (M)
    const int r0 = (lane >> 4) << 2;
    const int col = lane & 15;
#pragma unroll
    for (int mt = 0; mt < 4; ++mt) {
        const int tbase = m0 + wm * 64 + mt * 16 + r0;
        float as[4];
#pragma unroll
        for (int r = 0; r < 4; ++r) as[r] = a_scale[tbase + r];
#pragma unroll
        for (int nt = 0; nt < 4; ++nt) {
            const int o = n0 + wn * 64 + nt * 16 + col;
            const float wsc = w_scale[o];
#pragma unroll
            for (int r = 0; r < 4; ++r) {
                float v = (float)acc[mt][nt][r] * as[r] * wsc;
                // reference casts to fp16; harness stores output as f32
                out[(size_t)(tbase + r) * 4096 + o] = __half2float(__float2half_rn(v));
            }
        }
    }
}

extern "C" void kernel_launch(void* const* d_in, const int* in_sizes, int n_in,
                              void* d_out, int out_size, void* d_ws, size_t ws_size,
                              hipStream_t stream) {
    const float* input_act = (const float*)d_in[0];  // [4,2048,4096] = [8192,4096]
    const float* weight    = (const float*)d_in[1];  // [4096,4096]
    float* out = (float*)d_out;

    const int K = 4096, O = 4096, T = 8192;

    // workspace layout: x_q (32 MiB) | w_q (16 MiB) | a_scale (32 KB) | w_scale (16 KB)
    int8_t* x_q = (int8_t*)d_ws;
    int8_t* w_q = x_q + (size_t)T * K;
    float* a_scale = (float*)(w_q + (size_t)O * K);
    float* w_scale = a_scale + T;

    quant_rows<<<T, 256, 0, stream>>>(input_act, x_q, a_scale, K);
    quant_rows<<<O, 256, 0, stream>>>(weight, w_q, w_scale, K);

    dim3 grid(O / 128, T / 128);  // (32, 64) = 2048 blocks
    gemm_i8<<<grid, 256, 0, stream>>>(x_q, w_q, a_scale, w_scale, out);
}